// Round 15
// baseline (545.432 us; speedup 1.0000x reference)
//
#include <hip/hip_runtime.h>
#include <hip/hip_bf16.h>
#include <cstdint>

// U: 1024x1024, V: 2048x2048, out = Qu @ Qv[:1024,:]  (f32 1024x2048)
#define CI 1024
#define CO 2048
#define LP 40   // LDS row pitch in u16: 80 B rows, 16B-aligned -> b128 reads, 2-way banks (free)

typedef float  fx4  __attribute__((ext_vector_type(4)));
typedef short  s16x4 __attribute__((ext_vector_type(4)));
typedef short  s16x8 __attribute__((ext_vector_type(8)));
typedef unsigned short u16;

#define MFMA(a,b,c) __builtin_amdgcn_mfma_f32_16x16x32_bf16((a),(b),(c),0,0,0)

__device__ __forceinline__ u16 f2b(float x) {
    __hip_bfloat16 h = __float2bfloat16(x);
    return __builtin_bit_cast(u16, h);
}
__device__ __forceinline__ float b2f(u16 u) {
    __hip_bfloat16 h = __builtin_bit_cast(__hip_bfloat16, u);
    return __bfloat162float(h);
}

// ---------------- setup kernels ----------------

__global__ __launch_bounds__(256) void colnorm2(const float* __restrict__ M, float* __restrict__ n2, int d) {
    int c = blockIdx.x * 256 + threadIdx.x;
    int r0 = blockIdx.y * 64;
    float s = 0.0f;
    for (int r = r0; r < r0 + 64; ++r) {
        float v = M[(size_t)r * d + c];
        s = fmaf(v, v, s);
    }
    atomicAdd(&n2[c], s);
}

__global__ __launch_bounds__(256) void trans_planes_n(const float* __restrict__ X, int d,
                                                      const float* __restrict__ n2,
                                                      u16* __restrict__ Th, u16* __restrict__ Tl) {
    __shared__ float tile[32][33];
    int t = threadIdx.x;
    int r = t >> 3, c4 = (t & 7) * 4;
    int bx = blockIdx.x, by = blockIdx.y;
    fx4 v = *(const fx4*)(X + (size_t)(by * 32 + r) * d + bx * 32 + c4);
    tile[r][c4 + 0] = v[0]; tile[r][c4 + 1] = v[1]; tile[r][c4 + 2] = v[2]; tile[r][c4 + 3] = v[3];
    __syncthreads();
    int a = bx * 32 + r;
    float sc = 1.0f / sqrtf(n2[a]);
    u16 h[4], l[4];
    #pragma unroll
    for (int j = 0; j < 4; ++j) {
        float f = tile[c4 + j][r] * sc;
        u16 hb = f2b(f);
        h[j] = hb;
        l[j] = f2b(f - b2f(hb));
    }
    size_t o = (size_t)a * d + by * 32 + c4;
    *(s16x4*)&Th[o] = *(s16x4*)&h[0];
    *(s16x4*)&Tl[o] = *(s16x4*)&l[0];
}

__global__ __launch_bounds__(256) void planes_n(const float* __restrict__ X, int d,
                                                const float* __restrict__ n2,
                                                u16* __restrict__ Ph, u16* __restrict__ Pl) {
    size_t idx = ((size_t)blockIdx.x * 256 + threadIdx.x) * 8;
    int c = (int)(idx & (size_t)(d - 1));
    fx4 v0 = *(const fx4*)(X + idx);
    fx4 v1 = *(const fx4*)(X + idx + 4);
    u16 h[8], l[8];
    #pragma unroll
    for (int j = 0; j < 8; ++j) {
        float f = ((j < 4) ? v0[j] : v1[j - 4]) * (1.0f / sqrtf(n2[c + j]));
        u16 hb = f2b(f);
        h[j] = hb;
        l[j] = f2b(f - b2f(hb));
    }
    *(s16x4*)&Ph[idx]     = *(s16x4*)&h[0];
    *(s16x4*)&Ph[idx + 4] = *(s16x4*)&h[4];
    *(s16x4*)&Pl[idx]     = *(s16x4*)&l[0];
    *(s16x4*)&Pl[idx + 4] = *(s16x4*)&l[4];
}

__global__ __launch_bounds__(256) void planes_conv(const float* __restrict__ X,
                                                   u16* __restrict__ Ph, u16* __restrict__ Pl) {
    size_t idx = ((size_t)blockIdx.x * 256 + threadIdx.x) * 8;
    fx4 v0 = *(const fx4*)(X + idx);
    fx4 v1 = *(const fx4*)(X + idx + 4);
    u16 h[8], l[8];
    #pragma unroll
    for (int j = 0; j < 8; ++j) {
        float f = (j < 4) ? v0[j] : v1[j - 4];
        u16 hb = f2b(f);
        h[j] = hb;
        l[j] = f2b(f - b2f(hb));
    }
    *(s16x4*)&Ph[idx]     = *(s16x4*)&h[0];
    *(s16x4*)&Ph[idx + 4] = *(s16x4*)&h[4];
    *(s16x4*)&Pl[idx]     = *(s16x4*)&l[0];
    *(s16x4*)&Pl[idx + 4] = *(s16x4*)&l[4];
}

// ---------------- MFMA helpers (b128 LDS path) ----------------
__device__ __forceinline__ void mma_step(const u16 Ah[][LP], const u16 Al[][LP],
                                         const u16 Bh[][LP], const u16 Bl[][LP],
                                         int wr, int wc, int lane, fx4 acc[2][2]) {
    int kb = (lane >> 4) * 8;
    int rl = lane & 15;
    s16x8 ah[2], al[2], bh[2], bl[2];
    #pragma unroll
    for (int f = 0; f < 2; ++f) {
        int ra = wr * 32 + f * 16 + rl;
        ah[f] = *(const s16x8*)&Ah[ra][kb];
        al[f] = *(const s16x8*)&Al[ra][kb];
        int rb = wc * 32 + f * 16 + rl;
        bh[f] = *(const s16x8*)&Bh[rb][kb];
        bl[f] = *(const s16x8*)&Bl[rb][kb];
    }
    #pragma unroll
    for (int i = 0; i < 2; ++i)
        #pragma unroll
        for (int j = 0; j < 2; ++j) {
            acc[i][j] = MFMA(ah[i], bh[j], acc[i][j]);
            acc[i][j] = MFMA(ah[i], bl[j], acc[i][j]);
            acc[i][j] = MFMA(al[i], bh[j], acc[i][j]);
        }
}

struct PF { s16x8 h, l; };
__device__ __forceinline__ PF fetch_pl(const u16* __restrict__ Ph, const u16* __restrict__ Pl, int ld,
                                       int n0, int k0, int t) {
    int row = t >> 2, kc = (t & 3) * 8;
    size_t o = (size_t)(n0 + row) * ld + k0 + kc;
    PF f;
    f.h = *(const s16x8*)(Ph + o);
    f.l = *(const s16x8*)(Pl + o);
    return f;
}
__device__ __forceinline__ void commit_pl(const PF& f, u16 Dh[][LP], u16 Dl[][LP], int t) {
    int row = t >> 2, kc = (t & 3) * 8;
    *(s16x8*)&Dh[row][kc] = f.h;
    *(s16x8*)&Dl[row][kc] = f.l;
}

struct FF { fx4 v0, v1; };
template<int NPART>
__device__ __forceinline__ FF fetch_fsum(const float* __restrict__ A, int ldA, size_t pstride,
                                         int m0, int k0, int t) {
    int row = t >> 2, kc = (t & 3) * 8;
    const float* p = A + (size_t)(m0 + row) * ldA + k0 + kc;
    FF f;
    f.v0 = *(const fx4*)p;
    f.v1 = *(const fx4*)(p + 4);
    #pragma unroll
    for (int s = 1; s < NPART; ++s) {
        const float* q = p + (size_t)s * pstride;
        f.v0 += *(const fx4*)q;
        f.v1 += *(const fx4*)(q + 4);
    }
    return f;
}
__device__ __forceinline__ void commit_f32(const FF& f, u16 Dh[][LP], u16 Dl[][LP], int t) {
    int row = t >> 2, kc = (t & 3) * 8;
    u16 h[8], l[8];
    #pragma unroll
    for (int j = 0; j < 8; ++j) {
        float v = (j < 4) ? f.v0[j] : f.v1[j - 4];
        u16 hb = f2b(v);
        h[j] = hb;
        l[j] = f2b(v - b2f(hb));
    }
    *(s16x8*)&Dh[row][kc] = *(s16x8*)&h[0];
    *(s16x8*)&Dl[row][kc] = *(s16x8*)&l[0];
}

// ---------------- unified gram/Nt tile jobs ----------------
struct GJob {
    const u16* Ph; const u16* Pl; int ld;
    int a, b;
    float* out; int ldO;
};

__device__ __forceinline__ GJob gdecode(int t,
                                        const u16* Uh, const u16* Ul, const u16* Vh, const u16* Vl,
                                        float* Sd, float* Nt64, float* Nt128, float* Nt256, float* Nt512) {
    GJob g;
    if (t < 48) {
        bool isU = t < 16; int off = 64 * (isU ? t : t - 16);
        g.Ph = isU ? Uh : Vh; g.Pl = isU ? Ul : Vl; g.ld = isU ? CI : CO;
        g.a = off; g.b = off;
        g.out = Sd + (size_t)t * 4096; g.ldO = 64;
    } else if (t < 72) {
        int j = t - 48; bool isU = j < 8; int p = isU ? j : j - 8;
        int c0 = 128 * p, r1 = c0 + 64;
        g.Ph = isU ? Uh : Vh; g.Pl = isU ? Ul : Vl; g.ld = isU ? CI : CO;
        g.a = r1; g.b = c0;
        g.out = Nt64 + (size_t)j * 4096; g.ldO = 64;
    } else if (t < 120) {
        int j = t - 72; int pair = j >> 2, q = j & 3, my = q >> 1, mx = q & 1;
        bool isU = pair < 4; int p = isU ? pair : pair - 4;
        int c0 = 256 * p, r1 = c0 + 128;
        g.Ph = isU ? Uh : Vh; g.Pl = isU ? Ul : Vl; g.ld = isU ? CI : CO;
        g.a = r1 + 64 * my; g.b = c0 + 64 * mx;
        g.out = Nt128 + (size_t)pair * 16384 + (size_t)(64 * my) * 128 + 64 * mx; g.ldO = 128;
    } else if (t < 216) {
        int j = t - 120; int pair = j >> 4, q = j & 15, my = q >> 2, mx = q & 3;
        bool isU = pair < 2; int p = isU ? pair : pair - 2;
        int c0 = 512 * p, r1 = c0 + 256;
        g.Ph = isU ? Uh : Vh; g.Pl = isU ? Ul : Vl; g.ld = isU ? CI : CO;
        g.a = r1 + 64 * my; g.b = c0 + 64 * mx;
        g.out = Nt256 + (size_t)pair * 65536 + (size_t)(64 * my) * 256 + 64 * mx; g.ldO = 256;
    } else {
        int j = t - 216; int pair = j >> 6, q = j & 63, my = q >> 3, mx = q & 7;
        int c0 = 1024 * pair, r1 = c0 + 512;   // V only
        g.Ph = Vh; g.Pl = Vl; g.ld = CO;
        g.a = r1 + 64 * my; g.b = c0 + 64 * mx;
        g.out = Nt512 + (size_t)pair * 262144 + (size_t)(64 * my) * 512 + 64 * mx; g.ldO = 512;
    }
    return g;
}

__global__ __launch_bounds__(256) void gram_nt_sk(const u16* __restrict__ Uh, const u16* __restrict__ Ul,
                                                  const u16* __restrict__ Vh, const u16* __restrict__ Vl,
                                                  float* Sd, float* Nt64, float* Nt128, float* Nt256, float* Nt512,
                                                  float* __restrict__ Gp) {
    int tt = blockIdx.x, ks = blockIdx.y;
    GJob g = gdecode(tt, Uh, Ul, Vh, Vl, Sd, Nt64, Nt128, Nt256, Nt512);
    bool same = (g.a == g.b);
    int kchunk = g.ld >> 3;
    int kb = ks * kchunk;
    float* C = Gp + ((size_t)tt * 8 + ks) * 4096;
    __shared__ u16 Ah[64][LP], Al[64][LP], Bh_[64][LP], Bl_[64][LP];
    int t = threadIdx.x, lane = t & 63, w = t >> 6, wr = w >> 1, wc = w & 1;
    fx4 acc[2][2] = {};
    PF fa = fetch_pl(g.Ph, g.Pl, g.ld, g.a, kb, t);
    PF fb;
    if (!same) fb = fetch_pl(g.Ph, g.Pl, g.ld, g.b, kb, t);
    int nt = kchunk >> 5;
    for (int it = 0; it < nt; ++it) {
        commit_pl(fa, Ah, Al, t);
        if (!same) commit_pl(fb, Bh_, Bl_, t);
        __syncthreads();
        if (it + 1 < nt) {
            int k0 = kb + (it + 1) * 32;
            fa = fetch_pl(g.Ph, g.Pl, g.ld, g.a, k0, t);
            if (!same) fb = fetch_pl(g.Ph, g.Pl, g.ld, g.b, k0, t);
        }
        mma_step(Ah, Al, same ? Ah : Bh_, same ? Al : Bl_, wr, wc, lane, acc);
        __syncthreads();
    }
    #pragma unroll
    for (int fr = 0; fr < 2; ++fr)
        #pragma unroll
        for (int fc = 0; fc < 2; ++fc) {
            int row = wr * 32 + fr * 16 + ((lane >> 4) << 2);
            int col = wc * 32 + fc * 16 + (lane & 15);
            #pragma unroll
            for (int r = 0; r < 4; ++r)
                C[(size_t)(row + r) * 64 + col] = acc[fr][fc][r];
        }
}

__global__ __launch_bounds__(256) void gcombine(const float* __restrict__ Gp,
                                                const u16* Uh, const u16* Ul, const u16* Vh, const u16* Vl,
                                                float* Sd, float* Nt64, float* Nt128, float* Nt256, float* Nt512) {
    int tt = blockIdx.x;
    GJob g = gdecode(tt, Uh, Ul, Vh, Vl, Sd, Nt64, Nt128, Nt256, Nt512);
    const float* base = Gp + (size_t)tt * 8 * 4096;
    for (int i = threadIdx.x; i < 4096; i += 256) {
        float s = 0.0f;
        #pragma unroll
        for (int ks = 0; ks < 8; ++ks) s += base[(size_t)ks * 4096 + i];
        g.out[(size_t)(i >> 6) * g.ldO + (i & 63)] = s;
    }
}

// ---------------- diag 64-block inverse ----------------
__global__ __launch_bounds__(64) void diag_inv64(const float* __restrict__ Sd,
                                                 float* __restrict__ Ttu, float* __restrict__ Ttv) {
    int j = blockIdx.x;
    int y = blockIdx.y;
    const float* S = Sd + (size_t)y * 4096;
    float* T; int ldT, off;
    if (y < 16) { T = Ttu; ldT = CI; off = 64 * y; }
    else        { T = Ttv; ldT = CO; off = 64 * (y - 16); }
    float* Trow = T + (size_t)(off + j) * ldT + off;
    int l = threadIdx.x;
    float x = (l == j) ? 2.0f : 0.0f;
    float a = 0.0f;
    int jpad = (j + 7) & ~7;
    float q0=0,q1=0,q2=0,q3=0,q4=0,q5=0,q6=0,q7=0;
#define LR(Q, R) { int _r = (R); if (_r >= 1 && _r <= j) Q = S[(size_t)_r * 64 + l]; }
    LR(q0, jpad - 0) LR(q1, jpad - 1) LR(q2, jpad - 2) LR(q3, jpad - 3)
    LR(q4, jpad - 4) LR(q5, jpad - 5) LR(q6, jpad - 6) LR(q7, jpad - 7)
#define ST(Q) { \
    float yk = __shfl(x, k); \
    a = fmaf(Q, yk, a); \
    if (k <= j && l == k - 1) x = -2.0f * a; \
    int pr = k - 8; \
    if (pr >= 1) Q = S[(size_t)pr * 64 + l]; \
    --k; }
    int k = jpad;
    int ng = jpad >> 3;
    for (int g = 0; g < ng; ++g) {
        ST(q0) ST(q1) ST(q2) ST(q3) ST(q4) ST(q5) ST(q6) ST(q7)
    }
#undef ST
#undef LR
    Trow[l] = x;
}

// ---------------- merge level s=64: fused ----------------
__global__ __launch_bounds__(256) void merge64_fused(const float* __restrict__ Nt64,
                                                     float* __restrict__ Ttu, float* __restrict__ Ttv) {
    int p = blockIdx.x;
    bool isU = p < 8;
    float* Tt = isU ? Ttu : Ttv;
    int ldT = isU ? CI : CO;
    int pp = isU ? p : p - 8;
    int c0 = 128 * pp, r1 = c0 + 64;
    __shared__ float A[64][65], B[64][65], Tm[64][65];
    int t = threadIdx.x;
    int r = t >> 2, c = (t & 3) * 16;
    #pragma unroll
    for (int j = 0; j < 16; ++j) A[r][c + j] = Nt64[(size_t)p * 4096 + (size_t)r * 64 + c + j];
    #pragma unroll
    for (int j = 0; j < 16; ++j) B[r][c + j] = Tt[(size_t)(c0 + r) * ldT + c0 + c + j];
    __syncthreads();
    float acc[16];
    #pragma unroll
    for (int j = 0; j < 16; ++j) acc[j] = 0.0f;
    for (int k = 0; k < 64; ++k) {
        float av = A[r][k];
        #pragma unroll
        for (int j = 0; j < 16; ++j) acc[j] = fmaf(av, B[k][c + j], acc[j]);
    }
    __syncthreads();
    #pragma unroll
    for (int j = 0; j < 16; ++j) Tm[r][c + j] = acc[j];
    #pragma unroll
    for (int j = 0; j < 16; ++j) A[r][c + j] = Tt[(size_t)(r1 + r) * ldT + r1 + c + j];
    __syncthreads();
    #pragma unroll
    for (int j = 0; j < 16; ++j) acc[j] = 0.0f;
    for (int k = 0; k < 64; ++k) {
        float av = A[r][k];
        #pragma unroll
        for (int j = 0; j < 16; ++j) acc[j] = fmaf(av, Tm[k][c + j], acc[j]);
    }
    #pragma unroll
    for (int j = 0; j < 16; ++j)
        Tt[(size_t)(r1 + r) * ldT + c0 + c + j] = -acc[j];
}

// ---------------- fp32 split-K merge GEMMs ----------------
__device__ __forceinline__ void fgemm_sk_body(const float* __restrict__ A, int lda,
                                              const float* __restrict__ B, int ldb,
                                              float* __restrict__ P, int kb, int klen) {
    int m0 = blockIdx.y * 64, n0 = blockIdx.x * 64;
    __shared__ float As[16][64];
    __shared__ float Bs[16][64];
    int tid = threadIdx.x;
    int tm = (tid >> 4) * 8, tn = (tid & 15) * 4;
    int ar = tid >> 2, ac = (tid & 3) * 4;
    int bk = tid >> 4, bn = (tid & 15) * 4;
    float acc[8][4] = {};
    for (int k0 = kb; k0 < kb + klen; k0 += 16) {
        #pragma unroll
        for (int p = 0; p < 2; ++p) {
            int r = ar + p * 32;
            fx4 av = *(const fx4*)(A + (size_t)(m0 + r) * lda + k0 + ac);
            As[ac + 0][r] = av[0]; As[ac + 1][r] = av[1]; As[ac + 2][r] = av[2]; As[ac + 3][r] = av[3];
        }
        #pragma unroll
        for (int p = 0; p < 2; ++p) {
            int kk = bk + p * 8;
            *(fx4*)&Bs[kk][bn] = *(const fx4*)(B + (size_t)(k0 + kk) * ldb + n0 + bn);
        }
        __syncthreads();
        #pragma unroll
        for (int k = 0; k < 16; ++k) {
            fx4 alo = *(const fx4*)&As[k][tm];
            fx4 ahi = *(const fx4*)&As[k][tm + 4];
            fx4 bv  = *(const fx4*)&Bs[k][tn];
            float aa[8] = {alo[0], alo[1], alo[2], alo[3], ahi[0], ahi[1], ahi[2], ahi[3]};
            float bb[4] = {bv[0], bv[1], bv[2], bv[3]};
            #pragma unroll
            for (int i = 0; i < 8; ++i)
                #pragma unroll
                for (int jj = 0; jj < 4; ++jj) acc[i][jj] = fmaf(aa[i], bb[jj], acc[i][jj]);
        }
        __syncthreads();
    }
    #pragma unroll
    for (int i = 0; i < 8; ++i) {
        fx4 v = { acc[i][0], acc[i][1], acc[i][2], acc[i][3] };
        *(fx4*)(P + (size_t)(tm + i) * 64 + tn) = v;
    }
}

__global__ __launch_bounds__(128) void merge_a_sk(const float* __restrict__ NtL, int s, int KS,
                                                  const float* __restrict__ Ttu, const float* __restrict__ Ttv,
                                                  int npu, float* __restrict__ Mp) {
    int z = blockIdx.z;
    int pair = z / KS, ks = z % KS;
    const float* Tt; int ldT, p;
    if (pair < npu) { Tt = Ttu; ldT = CI; p = pair; } else { Tt = Ttv; ldT = CO; p = pair - npu; }
    int c0 = 2 * s * p;
    int gx = s >> 6;
    int tile = (pair * gx + blockIdx.y) * gx + blockIdx.x;
    int klen = s / KS;
    fgemm_sk_body(NtL + (size_t)pair * s * s, s, Tt + (size_t)c0 * ldT + c0, ldT,
                  Mp + ((size_t)tile * KS + ks) * 4096, ks * klen, klen);
}

__global__ __launch_bounds__(128) void merge_b_sk(const float* __restrict__ tmp, int s, int KS,
                                                  const float* __restrict__ Ttu, const float* __restrict__ Ttv,
                                                  int npu, float* __restrict__ Mp) {
    int z = blockIdx.z;
    int pair = z / KS, ks = z % KS;
    const float* Tt; int ldT, p;
    if (pair < npu) { Tt = Ttu; ldT = CI; p = pair; } else { Tt = Ttv; ldT = CO; p = pair - npu; }
    int c0 = 2 * s * p, r1 = c0 + s;
    int gx = s >> 6;
    int tile = (pair * gx + blockIdx.y) * gx + blockIdx.x;
    int klen = s / KS;
    fgemm_sk_body(Tt + (size_t)r1 * ldT + r1, ldT, tmp + (size_t)pair * s * s, s,
                  Mp + ((size_t)tile * KS + ks) * 4096, ks * klen, klen);
}

__global__ __launch_bounds__(256) void macomb(const float* __restrict__ Mp, int KS, int s,
                                              float* __restrict__ tmp) {
    int tile = blockIdx.x;
    int gx = s >> 6, per = gx * gx;
    int pair = tile / per, rem = tile % per, by = rem / gx, bx = rem % gx;
    float* dst = tmp + (size_t)pair * s * s + (size_t)(by * 64) * s + bx * 64;
    const float* base = Mp + (size_t)tile * KS * 4096;
    for (int i = threadIdx.x; i < 4096; i += 256) {
        float v = 0.0f;
        for (int k = 0; k < KS; ++k) v += base[(size_t)k * 4096 + i];
        dst[(size_t)(i >> 6) * s + (i & 63)] = v;
    }
}

__global__ __launch_bounds__(256) void mbcomb(const float* __restrict__ Mp, int KS, int s, int npu,
                                              float* __restrict__ Ttu, float* __restrict__ Ttv) {
    int tile = blockIdx.x;
    int gx = s >> 6, per = gx * gx;
    int pair = tile / per, rem = tile % per, by = rem / gx, bx = rem % gx;
    float* Tt; int ldT, p;
    if (pair < npu) { Tt = Ttu; ldT = CI; p = pair; } else { Tt = Ttv; ldT = CO; p = pair - npu; }
    int c0 = 2 * s * p, r1 = c0 + s;
    float* dst = Tt + (size_t)(r1 + by * 64) * ldT + c0 + bx * 64;
    const float* base = Mp + (size_t)tile * KS * 4096;
    for (int i = threadIdx.x; i < 4096; i += 256) {
        float v = 0.0f;
        for (int k = 0; k < KS; ++k) v += base[(size_t)k * 4096 + i];
        dst[(size_t)(i >> 6) * ldT + (i & 63)] = -v;
    }
}

// ---------------- split-K chain GEMM (planes A and B) ----------------
__global__ __launch_bounds__(256) void gemm_pp_sk(const u16* __restrict__ Ah_, const u16* __restrict__ Al_, int ldA,
                                                  const u16* __restrict__ Bh0, const u16* __restrict__ Bl0, int ldB,
                                                  float* __restrict__ Pp, int kchunk) {
    int N = gridDim.x * 64;
    size_t MN = (size_t)gridDim.x * gridDim.y * 4096;
    float* C = Pp + (size_t)blockIdx.z * MN;
    int kb = blockIdx.z * kchunk;
    __shared__ u16 Ah[64][LP], Al[64][LP], Bh_[64][LP], Bl_[64][LP];
    int t = threadIdx.x, lane = t & 63, w = t >> 6, wr = w >> 1, wc = w & 1;
    int m0 = blockIdx.y * 64, n0 = blockIdx.x * 64;
    fx4 acc[2][2] = {};
    PF fa = fetch_pl(Ah_, Al_, ldA, m0, kb, t);
    PF fb = fetch_pl(Bh0, Bl0, ldB, n0, kb, t);
    int nt = kchunk >> 5;
    for (int it = 0; it < nt; ++it) {
        commit_pl(fa, Ah, Al, t);
        commit_pl(fb, Bh_, Bl_, t);
        __syncthreads();
        if (it + 1 < nt) {
            int k0 = kb + (it + 1) * 32;
            fa = fetch_pl(Ah_, Al_, ldA, m0, k0, t);
            fb = fetch_pl(Bh0, Bl0, ldB, n0, k0, t);
        }
        mma_step(Ah, Al, Bh_, Bl_, wr, wc, lane, acc);
        __syncthreads();
    }
    #pragma unroll
    for (int fr = 0; fr < 2; ++fr)
        #pragma unroll
        for (int fc = 0; fc < 2; ++fc) {
            int row = m0 + wr * 32 + fr * 16 + ((lane >> 4) << 2);
            int col = n0 + wc * 32 + fc * 16 + (lane & 15);
            #pragma unroll
            for (int r = 0; r < 4; ++r)
                C[(size_t)(row + r) * N + col] = acc[fr][fc][r];
        }
}

// ---------------- split-K chain GEMM: A = sum of NPART f32 partials (fused combine) ----------------
template<int NPART>
__global__ __launch_bounds__(256) void gemm_fs_sk(const float* __restrict__ Asrc, int ldA, size_t pstride,
                                                  const u16* __restrict__ Bh0, const u16* __restrict__ Bl0, int ldB,
                                                  float* __restrict__ Pp, int kchunk) {
    int N = gridDim.x * 64;
    size_t MN = (size_t)gridDim.x * gridDim.y * 4096;
    float* C = Pp + (size_t)blockIdx.z * MN;
    int kb = blockIdx.z * kchunk;
    __shared__ u16 Ah[64][LP], Al[64][LP], Bh_[64][LP], Bl_[64][LP];
    int t = threadIdx.x, lane = t & 63, w = t >> 6, wr = w >> 1, wc = w & 1;
    int m0 = blockIdx.y * 64, n0 = blockIdx.x * 64;
    fx4 acc[2][2] = {};
    FF fa = fetch_fsum<NPART>(Asrc, ldA, pstride, m0, kb, t);
    PF fb = fetch_pl(Bh0, Bl0, ldB, n0, kb, t);
    int nt = kchunk >> 5;
    for (int it = 0; it < nt; ++it) {
        commit_f32(fa, Ah, Al, t);
        commit_pl(fb, Bh_, Bl_, t);
        __syncthreads();
        if (it + 1 < nt) {
            int k0 = kb + (it + 1) * 32;
            fa = fetch_fsum<NPART>(Asrc, ldA, pstride, m0, k0, t);
            fb = fetch_pl(Bh0, Bl0, ldB, n0, k0, t);
        }
        mma_step(Ah, Al, Bh_, Bl_, wr, wc, lane, acc);
        __syncthreads();
    }
    #pragma unroll
    for (int fr = 0; fr < 2; ++fr)
        #pragma unroll
        for (int fc = 0; fc < 2; ++fc) {
            int row = m0 + wr * 32 + fr * 16 + ((lane >> 4) << 2);
            int col = n0 + wc * 32 + fc * 16 + (lane & 15);
            #pragma unroll
            for (int r = 0; r < 4; ++r)
                C[(size_t)(row + r) * N + col] = acc[fr][fc][r];
        }
}

// ---------------- combine: epi(sum_s Pp[s]) -> f32 C and/or bf16 planes ----------------
// MODE: 0 sum ; 1 I-sum ; 2 aux-sum ; 3 C-sum (reads C) ; 4 (col<CI?aux:0)-sum
// OUT bit0: write f32 C ; bit1: write planes Ph/Pl
template<int MODE, int OUT>
__global__ __launch_bounds__(256) void combine(const float* __restrict__ Pp, int S,
                                               const float* __restrict__ aux, int ldaux,
                                               float* __restrict__ C,
                                               u16* __restrict__ Ph, u16* __restrict__ Pl, int N) {
    size_t MN = (size_t)gridDim.x * 2048;
    int gid = blockIdx.x * 256 + threadIdx.x;
    size_t idx = (size_t)gid * 8;
    int nv = N >> 3;
    int row = gid / nv, col = (gid % nv) * 8;
    fx4 s0 = *(const fx4*)(Pp + idx);
    fx4 s1 = *(const fx4*)(Pp + idx + 4);
    for (int s = 1; s < S; ++s) {
        const float* p = Pp + (size_t)s * MN + idx;
        s0 += *(const fx4*)p;
        s1 += *(const fx4*)(p + 4);
    }
    float out[8];
    #pragma unroll
    for (int j = 0; j < 8; ++j) {
        float a = (j < 4) ? s0[j] : s1[j - 4];
        if (MODE == 0)      out[j] = a;
        else if (MODE == 1) out[j] = ((col + j) == row ? 1.0f : 0.0f) - a;
        else if (MODE == 2) out[j] = aux[(size_t)row * ldaux + col + j] - a;
        else if (MODE == 3) out[j] = C[(size_t)row * N + col + j] - a;
        else                out[j] = ((col + j) < CI ? aux[(size_t)row * ldaux + col + j] : 0.0f) - a;
    }
    size_t o = (size_t)row * N + col;
    if (OUT & 1) {
        *(fx4*)(C + o)     = *(fx4*)&out[0];
        *(fx4*)(C + o + 4) = *(fx4*)&out[4];
    }
    if (OUT & 2) {
        u16 h[8], l[8];
        #pragma unroll
        for (int j = 0; j < 8; ++j) {
            u16 hb = f2b(out[j]);
            h[j] = hb;
            l[j] = f2b(out[j] - b2f(hb));
        }
        *(s16x4*)&Ph[o]     = *(s16x4*)&h[0];
        *(s16x4*)&Ph[o + 4] = *(s16x4*)&h[4];
        *(s16x4*)&Pl[o]     = *(s16x4*)&l[0];
        *(s16x4*)&Pl[o + 4] = *(s16x4*)&l[4];
    }
}

extern "C" void kernel_launch(void* const* d_in, const int* in_sizes, int n_in,
                              void* d_out, int out_size, void* d_ws, size_t ws_size,
                              hipStream_t stream) {
    const float* U = (const float*)d_in[0];   // 1024x1024
    const float* V = (const float*)d_in[1];   // 2048x2048
    float* W = (float*)d_out;                 // 1024x2048

    char* ws = (char*)d_ws;
    u16*   Unth = (u16*)  (ws + ((size_t)0   << 20));  // 2 MB
    u16*   Untl = (u16*)  (ws + ((size_t)2   << 20));
    u16*   Unh  = (u16*)  (ws + ((size_t)4   << 20));
    u16*   Unl  = (u16*)  (ws + ((size_t)6   << 20));
    u16*   Vnth = (u16*)  (ws + ((size_t)8   << 20));  // 8 MB
    u16*   Vntl = (u16*)  (ws + ((size_t)16  << 20));
    u16*   Vnh  = (u16*)  (ws + ((size_t)24  << 20));
    u16*   Vnl  = (u16*)  (ws + ((size_t)32  << 20));
    float* Ttu  = (float*)(ws + ((size_t)40  << 20));  // 4 MB
    float* Ttv  = (float*)(ws + ((size_t)44  << 20));  // 16 MB
    u16*   Mtuh = (u16*)  (ws + ((size_t)60  << 20));  // 2 MB
    u16*   Mtul = (u16*)  (ws + ((size_t)62  << 20));
    u16*   Mtvh = (u16*)  (ws + ((size_t)64  << 20));  // 8 MB
    u16*   Mtvl = (u16*)  (ws + ((size_t)72  << 20));
    float* Sd   = (float*)(ws + ((size_t)80  << 20));  // 0.75 MB
    float* NtA  = (float*)(ws + ((size_t)81  << 20));  // 4.85 MB
    float* tmp  = (float*)(ws + ((size_t)86  << 20));  // 2 MB
    float* Qp   = (float*)(ws + ((size_t)90  << 20));  // 4 MB (f32, aux)
    float* Qu   = (float*)(ws + ((size_t)98  << 20));  // 4 MB (f32, aux)
    float* n2u  = (float*)(ws + ((size_t)118 << 20));  // 12 KB
    float* n2v  = n2u + CI;
    float* Pp   = (float*)(ws + ((size_t)120 << 20));  // 16 MB chain partials (ping)
    float* Pq   = (float*)(ws + ((size_t)136 << 20));  // 16 MB chain partials (pong)
    float* Gp   = (float*)(ws + ((size_t)120 << 20));  // 45 MB gram/nt partials (pre-chain)
    float* Mp   = Gp;
    u16* Qph  = (u16*)(ws + ((size_t)172 << 20));  // 2 MB
    u16* Qpl  = (u16*)(ws + ((size_t)174 << 20));
    u16* Quh  = (u16*)(ws + ((size_t)180 << 20));  // 2 MB
    u16* Qul  = (u16*)(ws + ((size_t)182 << 20));
    u16* Wh   = (u16*)(ws + ((size_t)192 << 20));  // 4 MB
    u16* Wl   = (u16*)(ws + ((size_t)196 << 20));

    float* Nt64  = NtA;
    float* Nt128 = NtA + 98304;
    float* Nt256 = NtA + 294912;
    float* Nt512 = NtA + 688128;

    // 1) column norms
    hipMemsetAsync(n2u, 0, (CI + CO) * sizeof(float), stream);
    colnorm2<<<dim3(CI / 256, CI / 64), dim3(256), 0, stream>>>(U, n2u, CI);
    colnorm2<<<dim3(CO / 256, CO / 64), dim3(256), 0, stream>>>(V, n2v, CO);

    // 2) normalized planes
    trans_planes_n<<<dim3(CI / 32, CI / 32), dim3(256), 0, stream>>>(U, CI, n2u, Unth, Untl);
    trans_planes_n<<<dim3(CO / 32, CO / 32), dim3(256), 0, stream>>>(V, CO, n2v, Vnth, Vntl);
    planes_n<<<dim3(CI * CI / 2048), dim3(256), 0, stream>>>(U, CI, n2u, Unh, Unl);
    planes_n<<<dim3(CO * CO / 2048), dim3(256), 0, stream>>>(V, CO, n2v, Vnh, Vnl);

    // 3) ALL gram + Nt tiles
    gram_nt_sk<<<dim3(344, 8), dim3(256), 0, stream>>>(Unth, Untl, Vnth, Vntl,
                                                       Sd, Nt64, Nt128, Nt256, Nt512, Gp);
    gcombine<<<dim3(344), dim3(256), 0, stream>>>(Gp, Unth, Untl, Vnth, Vntl,
                                                  Sd, Nt64, Nt128, Nt256, Nt512);

    // 4) blocked triangular inverse
    hipMemsetAsync(Ttu, 0, (size_t)20 << 20, stream);
    diag_inv64<<<dim3(64, 48), dim3(64), 0, stream>>>(Sd, Ttu, Ttv);
    merge64_fused<<<dim3(24), dim3(256), 0, stream>>>(Nt64, Ttu, Ttv);
    merge_a_sk<<<dim3(2, 2, 48), dim3(128), 0, stream>>>(Nt128, 128, 4, Ttu, Ttv, 4, Mp);
    macomb<<<dim3(48), dim3(256), 0, stream>>>(Mp, 4, 128, tmp);
    merge_b_sk<<<dim3(2, 2, 48), dim3(128), 0, stream>>>(tmp, 128, 4, Ttu, Ttv, 4, Mp);
    mbcomb<<<dim3(48), dim3(256), 0, stream>>>(Mp, 4, 128, 4, Ttu, Ttv);
    merge_a_sk<<<dim3(4, 4, 24), dim3(128), 0, stream>>>(Nt256, 256, 4, Ttu, Ttv, 2, Mp);
    macomb<<<dim3(96), dim3(256), 0, stream>>>(Mp, 4, 256, tmp);
    merge_b_sk<<<dim3(4, 4, 24), dim3(128), 0, stream>>>(tmp, 256, 4, Ttu, Ttv, 2, Mp);
    mbcomb<<<dim3(96), dim3(256), 0, stream>>>(Mp, 4, 256, 2, Ttu, Ttv);
    merge_a_sk<<<dim3(8, 8, 16), dim3(128), 0, stream>>>(Nt512, 512, 8, Ttu, Ttv, 0, Mp);
    macomb<<<dim3(128), dim3(256), 0, stream>>>(Mp, 8, 512, tmp);
    merge_b_sk<<<dim3(8, 8, 16), dim3(128), 0, stream>>>(tmp, 512, 8, Ttu, Ttv, 0, Mp);
    mbcomb<<<dim3(128), dim3(256), 0, stream>>>(Mp, 8, 512, 0, Ttu, Ttv);

    // 5) T planes
    planes_conv<<<dim3(CI * CI / 2048), dim3(256), 0, stream>>>(Ttu, Mtuh, Mtul);
    planes_conv<<<dim3(CO * CO / 2048), dim3(256), 0, stream>>>(Ttv, Mtvh, Mtvl);

    // 6) U series: plain-sum combines fused into consumer A-stage (partial strides checked vs producer grids)
    gemm_pp_sk<<<dim3(8, 16, 4), dim3(256), 0, stream>>>(Unh, Unl, CI, Mtuh, Mtul, CI, Pp, 128);
    // X1(=sum Pp, 1024x512) @ Un^T-planes -> Pq      [pstride = 8*16*4096 = 512K]
    gemm_fs_sk<4><<<dim3(16, 16, 4), dim3(256), 0, stream>>>(Pp, 512, (size_t)524288, Unh, Unl, CI, Pq, 128);
    combine<1, 3><<<dim3(CI * CI / 2048), dim3(256), 0, stream>>>(Pq, 4, nullptr, 0, Qp, Qph, Qpl, CI);
    gemm_pp_sk<<<dim3(8, 16, 4), dim3(256), 0, stream>>>(Qph, Qpl, CI, Unth + (size_t)512 * CI, Untl + (size_t)512 * CI, CI, Pp, 256);
    // H2u = (sum Pp = H1u, 1024x512) @ Mtu22 -> Pq   [pstride = 512K]
    gemm_fs_sk<4><<<dim3(8, 16, 4), dim3(256), 0, stream>>>(Pp, 512, (size_t)524288,
                                                            Mtuh + (size_t)512 * CI + 512, Mtul + (size_t)512 * CI + 512, CI, Pq, 128);
    // (sum Pq = H2u) @ Un[:,512:] -> Pp              [pstride = 8*16*4096 = 512K]
    gemm_fs_sk<4><<<dim3(16, 16, 4), dim3(256), 0, stream>>>(Pq, 512, (size_t)524288, Unh + 512, Unl + 512, CI, Pp, 128);
    combine<2, 3><<<dim3(CI * CI / 2048), dim3(256), 0, stream>>>(Pp, 4, Qp, CI, Qu, Quh, Qul, CI);

    // 7) V series
    gemm_pp_sk<<<dim3(16, 16, 4), dim3(256), 0, stream>>>(Quh, Qul, CI, Vnth, Vntl, CO, Pp, 256);
    // (sum Pp = H1, 1024x1024) @ Mtv11 -> Pq         [pstride = 16*16*4096 = 1M]
    gemm_fs_sk<4><<<dim3(16, 16, 4), dim3(256), 0, stream>>>(Pp, CI, (size_t)1048576, Mtvh, Mtvl, CO, Pq, 256);
    // (sum Pq = H2) @ Vn1 -> Pp                      [pstride = 1M]
    gemm_fs_sk<4><<<dim3(32, 16, 2), dim3(256), 0, stream>>>(Pq, CI, (size_t)1048576, Vnh, Vnl, CO, Pp, 512);
    combine<4, 3><<<dim3(CI * CO / 2048), dim3(256), 0, stream>>>(Pp, 2, Qu, CI, W, Wh, Wl, CO);
    gemm_pp_sk<<<dim3(16, 16, 4), dim3(256), 0, stream>>>(Wh, Wl, CO, Vnth + (size_t)1024 * CO, Vntl + (size_t)1024 * CO, CO, Pp, 512);
    // (sum Pp = H3, 1024x1024) @ Mtv22 -> Pq         [pstride = 1M]
    gemm_fs_sk<4><<<dim3(16, 16, 4), dim3(256), 0, stream>>>(Pp, CI, (size_t)1048576,
                                                             Mtvh + (size_t)1024 * CO + 1024, Mtvl + (size_t)1024 * CO + 1024, CO, Pq, 256);
    // (sum Pq = H4) @ Vn2 -> Pp                      [pstride = 1M]
    gemm_fs_sk<4><<<dim3(32, 16, 2), dim3(256), 0, stream>>>(Pq, CI, (size_t)1048576, Vnh + 1024, Vnl + 1024, CO, Pp, 512);
    combine<3, 1><<<dim3(CI * CO / 2048), dim3(256), 0, stream>>>(Pp, 2, nullptr, 0, W, nullptr, nullptr, CO);
}

// Round 16
// 499.981 us; speedup vs baseline: 1.0909x; 1.0909x over previous
//
#include <hip/hip_runtime.h>
#include <hip/hip_bf16.h>
#include <cstdint>

// U: 1024x1024, V: 2048x2048, out = Qu @ Qv[:1024,:]  (f32 1024x2048)
#define CI 1024
#define CO 2048
#define LP 36   // LDS row pitch in u16

typedef float  fx4  __attribute__((ext_vector_type(4)));
typedef short  s16x4 __attribute__((ext_vector_type(4)));
typedef short  s16x8 __attribute__((ext_vector_type(8)));
typedef unsigned short u16;

#define MFMA(a,b,c) __builtin_amdgcn_mfma_f32_16x16x32_bf16((a),(b),(c),0,0,0)

__device__ __forceinline__ u16 f2b(float x) {
    __hip_bfloat16 h = __float2bfloat16(x);
    return __builtin_bit_cast(u16, h);
}
__device__ __forceinline__ float b2f(u16 u) {
    __hip_bfloat16 h = __builtin_bit_cast(__hip_bfloat16, u);
    return __bfloat162float(h);
}

// ---------------- setup kernels ----------------

__global__ __launch_bounds__(256) void colnorm2(const float* __restrict__ M, float* __restrict__ n2, int d) {
    int c = blockIdx.x * 256 + threadIdx.x;
    int r0 = blockIdx.y * 64;
    float s = 0.0f;
    for (int r = r0; r < r0 + 64; ++r) {
        float v = M[(size_t)r * d + c];
        s = fmaf(v, v, s);
    }
    atomicAdd(&n2[c], s);
}

__global__ __launch_bounds__(256) void trans_planes_n(const float* __restrict__ X, int d,
                                                      const float* __restrict__ n2,
                                                      u16* __restrict__ Th, u16* __restrict__ Tl) {
    __shared__ float tile[32][33];
    int t = threadIdx.x;
    int r = t >> 3, c4 = (t & 7) * 4;
    int bx = blockIdx.x, by = blockIdx.y;
    fx4 v = *(const fx4*)(X + (size_t)(by * 32 + r) * d + bx * 32 + c4);
    tile[r][c4 + 0] = v[0]; tile[r][c4 + 1] = v[1]; tile[r][c4 + 2] = v[2]; tile[r][c4 + 3] = v[3];
    __syncthreads();
    int a = bx * 32 + r;
    float sc = 1.0f / sqrtf(n2[a]);
    u16 h[4], l[4];
    #pragma unroll
    for (int j = 0; j < 4; ++j) {
        float f = tile[c4 + j][r] * sc;
        u16 hb = f2b(f);
        h[j] = hb;
        l[j] = f2b(f - b2f(hb));
    }
    size_t o = (size_t)a * d + by * 32 + c4;
    *(s16x4*)&Th[o] = *(s16x4*)&h[0];
    *(s16x4*)&Tl[o] = *(s16x4*)&l[0];
}

__global__ __launch_bounds__(256) void planes_n(const float* __restrict__ X, int d,
                                                const float* __restrict__ n2,
                                                u16* __restrict__ Ph, u16* __restrict__ Pl) {
    size_t idx = ((size_t)blockIdx.x * 256 + threadIdx.x) * 8;
    int c = (int)(idx & (size_t)(d - 1));
    fx4 v0 = *(const fx4*)(X + idx);
    fx4 v1 = *(const fx4*)(X + idx + 4);
    u16 h[8], l[8];
    #pragma unroll
    for (int j = 0; j < 8; ++j) {
        float f = ((j < 4) ? v0[j] : v1[j - 4]) * (1.0f / sqrtf(n2[c + j]));
        u16 hb = f2b(f);
        h[j] = hb;
        l[j] = f2b(f - b2f(hb));
    }
    *(s16x4*)&Ph[idx]     = *(s16x4*)&h[0];
    *(s16x4*)&Ph[idx + 4] = *(s16x4*)&h[4];
    *(s16x4*)&Pl[idx]     = *(s16x4*)&l[0];
    *(s16x4*)&Pl[idx + 4] = *(s16x4*)&l[4];
}

__global__ __launch_bounds__(256) void planes_conv(const float* __restrict__ X,
                                                   u16* __restrict__ Ph, u16* __restrict__ Pl) {
    size_t idx = ((size_t)blockIdx.x * 256 + threadIdx.x) * 8;
    fx4 v0 = *(const fx4*)(X + idx);
    fx4 v1 = *(const fx4*)(X + idx + 4);
    u16 h[8], l[8];
    #pragma unroll
    for (int j = 0; j < 8; ++j) {
        float f = (j < 4) ? v0[j] : v1[j - 4];
        u16 hb = f2b(f);
        h[j] = hb;
        l[j] = f2b(f - b2f(hb));
    }
    *(s16x4*)&Ph[idx]     = *(s16x4*)&h[0];
    *(s16x4*)&Ph[idx + 4] = *(s16x4*)&h[4];
    *(s16x4*)&Pl[idx]     = *(s16x4*)&l[0];
    *(s16x4*)&Pl[idx + 4] = *(s16x4*)&l[4];
}

// ---------------- MFMA helpers ----------------
__device__ __forceinline__ void mma_step(const u16 Ah[][LP], const u16 Al[][LP],
                                         const u16 Bh[][LP], const u16 Bl[][LP],
                                         int wr, int wc, int lane, fx4 acc[2][2]) {
    int kb = (lane >> 4) * 8;
    int rl = lane & 15;
    s16x8 ah[2], al[2], bh[2], bl[2];
    #pragma unroll
    for (int f = 0; f < 2; ++f) {
        int ra = wr * 32 + f * 16 + rl;
        s16x4 p = *(const s16x4*)&Ah[ra][kb];
        s16x4 q = *(const s16x4*)&Ah[ra][kb + 4];
        ah[f] = __builtin_shufflevector(p, q, 0,1,2,3,4,5,6,7);
        p = *(const s16x4*)&Al[ra][kb];
        q = *(const s16x4*)&Al[ra][kb + 4];
        al[f] = __builtin_shufflevector(p, q, 0,1,2,3,4,5,6,7);
        int rb = wc * 32 + f * 16 + rl;
        p = *(const s16x4*)&Bh[rb][kb];
        q = *(const s16x4*)&Bh[rb][kb + 4];
        bh[f] = __builtin_shufflevector(p, q, 0,1,2,3,4,5,6,7);
        p = *(const s16x4*)&Bl[rb][kb];
        q = *(const s16x4*)&Bl[rb][kb + 4];
        bl[f] = __builtin_shufflevector(p, q, 0,1,2,3,4,5,6,7);
    }
    #pragma unroll
    for (int i = 0; i < 2; ++i)
        #pragma unroll
        for (int j = 0; j < 2; ++j) {
            acc[i][j] = MFMA(ah[i], bh[j], acc[i][j]);
            acc[i][j] = MFMA(ah[i], bl[j], acc[i][j]);
            acc[i][j] = MFMA(al[i], bh[j], acc[i][j]);
        }
}

// fetch (global -> regs) / commit (regs -> LDS) pairs for double-buffered pipeline
struct PF { s16x4 a, b, c, d; };
__device__ __forceinline__ PF fetch_pl(const u16* __restrict__ Ph, const u16* __restrict__ Pl, int ld,
                                       int n0, int k0, int t) {
    int row = t >> 2, kc = (t & 3) * 8;
    size_t o = (size_t)(n0 + row) * ld + k0 + kc;
    PF f;
    f.a = *(const s16x4*)(Ph + o);
    f.b = *(const s16x4*)(Ph + o + 4);
    f.c = *(const s16x4*)(Pl + o);
    f.d = *(const s16x4*)(Pl + o + 4);
    return f;
}
__device__ __forceinline__ void commit_pl(const PF& f, u16 Dh[][LP], u16 Dl[][LP], int t) {
    int row = t >> 2, kc = (t & 3) * 8;
    *(s16x4*)&Dh[row][kc]     = f.a;
    *(s16x4*)&Dh[row][kc + 4] = f.b;
    *(s16x4*)&Dl[row][kc]     = f.c;
    *(s16x4*)&Dl[row][kc + 4] = f.d;
}
struct FF { fx4 v0, v1; };
__device__ __forceinline__ FF fetch_f32(const float* __restrict__ A, int ldA, int m0, int k0, int t) {
    int row = t >> 2, kc = (t & 3) * 8;
    const float* p = A + (size_t)(m0 + row) * ldA + k0 + kc;
    FF f;
    f.v0 = *(const fx4*)p;
    f.v1 = *(const fx4*)(p + 4);
    return f;
}
__device__ __forceinline__ void commit_f32(const FF& f, u16 Dh[][LP], u16 Dl[][LP], int t) {
    int row = t >> 2, kc = (t & 3) * 8;
    u16 h[8], l[8];
    #pragma unroll
    for (int j = 0; j < 8; ++j) {
        float v = (j < 4) ? f.v0[j] : f.v1[j - 4];
        u16 hb = f2b(v);
        h[j] = hb;
        l[j] = f2b(v - b2f(hb));
    }
    *(s16x4*)&Dh[row][kc]     = *(s16x4*)&h[0];
    *(s16x4*)&Dh[row][kc + 4] = *(s16x4*)&h[4];
    *(s16x4*)&Dl[row][kc]     = *(s16x4*)&l[0];
    *(s16x4*)&Dl[row][kc + 4] = *(s16x4*)&l[4];
}

// ---------------- unified gram/Nt tile jobs ----------------
// 344 tiles of 64x64: [0,48) gram diag; [48,72) nt64; [72,120) nt128; [120,216) nt256; [216,344) nt512
struct GJob {
    const u16* Ph; const u16* Pl; int ld;
    int a, b;
    float* out; int ldO;
};

__device__ __forceinline__ GJob gdecode(int t,
                                        const u16* Uh, const u16* Ul, const u16* Vh, const u16* Vl,
                                        float* Sd, float* Nt64, float* Nt128, float* Nt256, float* Nt512) {
    GJob g;
    if (t < 48) {
        bool isU = t < 16; int off = 64 * (isU ? t : t - 16);
        g.Ph = isU ? Uh : Vh; g.Pl = isU ? Ul : Vl; g.ld = isU ? CI : CO;
        g.a = off; g.b = off;
        g.out = Sd + (size_t)t * 4096; g.ldO = 64;
    } else if (t < 72) {
        int j = t - 48; bool isU = j < 8; int p = isU ? j : j - 8;
        int c0 = 128 * p, r1 = c0 + 64;
        g.Ph = isU ? Uh : Vh; g.Pl = isU ? Ul : Vl; g.ld = isU ? CI : CO;
        g.a = r1; g.b = c0;
        g.out = Nt64 + (size_t)j * 4096; g.ldO = 64;
    } else if (t < 120) {
        int j = t - 72; int pair = j >> 2, q = j & 3, my = q >> 1, mx = q & 1;
        bool isU = pair < 4; int p = isU ? pair : pair - 4;
        int c0 = 256 * p, r1 = c0 + 128;
        g.Ph = isU ? Uh : Vh; g.Pl = isU ? Ul : Vl; g.ld = isU ? CI : CO;
        g.a = r1 + 64 * my; g.b = c0 + 64 * mx;
        g.out = Nt128 + (size_t)pair * 16384 + (size_t)(64 * my) * 128 + 64 * mx; g.ldO = 128;
    } else if (t < 216) {
        int j = t - 120; int pair = j >> 4, q = j & 15, my = q >> 2, mx = q & 3;
        bool isU = pair < 2; int p = isU ? pair : pair - 2;
        int c0 = 512 * p, r1 = c0 + 256;
        g.Ph = isU ? Uh : Vh; g.Pl = isU ? Ul : Vl; g.ld = isU ? CI : CO;
        g.a = r1 + 64 * my; g.b = c0 + 64 * mx;
        g.out = Nt256 + (size_t)pair * 65536 + (size_t)(64 * my) * 256 + 64 * mx; g.ldO = 256;
    } else {
        int j = t - 216; int pair = j >> 6, q = j & 63, my = q >> 3, mx = q & 7;
        int c0 = 1024 * pair, r1 = c0 + 512;   // V only
        g.Ph = Vh; g.Pl = Vl; g.ld = CO;
        g.a = r1 + 64 * my; g.b = c0 + 64 * mx;
        g.out = Nt512 + (size_t)pair * 262144 + (size_t)(64 * my) * 512 + 64 * mx; g.ldO = 512;
    }
    return g;
}

// one dispatch for ALL gram+Nt tiles, split-K 8, double-buffered; partials into Gp[(t*8+ks)*4096]
__global__ __launch_bounds__(256) void gram_nt_sk(const u16* __restrict__ Uh, const u16* __restrict__ Ul,
                                                  const u16* __restrict__ Vh, const u16* __restrict__ Vl,
                                                  float* Sd, float* Nt64, float* Nt128, float* Nt256, float* Nt512,
                                                  float* __restrict__ Gp) {
    int tt = blockIdx.x, ks = blockIdx.y;
    GJob g = gdecode(tt, Uh, Ul, Vh, Vl, Sd, Nt64, Nt128, Nt256, Nt512);
    bool same = (g.a == g.b);
    int kchunk = g.ld >> 3;
    int kb = ks * kchunk;
    float* C = Gp + ((size_t)tt * 8 + ks) * 4096;
    __shared__ u16 Ah[2][64][LP], Al[2][64][LP], Bh_[2][64][LP], Bl_[2][64][LP];
    int t = threadIdx.x, lane = t & 63, w = t >> 6, wr = w >> 1, wc = w & 1;
    fx4 acc[2][2] = {};
    PF fa = fetch_pl(g.Ph, g.Pl, g.ld, g.a, kb, t);
    PF fb;
    if (!same) fb = fetch_pl(g.Ph, g.Pl, g.ld, g.b, kb, t);
    commit_pl(fa, Ah[0], Al[0], t);
    if (!same) commit_pl(fb, Bh_[0], Bl_[0], t);
    __syncthreads();
    int nt = kchunk >> 5;
    for (int it = 0; it < nt; ++it) {
        int cur = it & 1;
        if (it + 1 < nt) {
            int k0 = kb + (it + 1) * 32;
            fa = fetch_pl(g.Ph, g.Pl, g.ld, g.a, k0, t);
            if (!same) fb = fetch_pl(g.Ph, g.Pl, g.ld, g.b, k0, t);
        }
        mma_step(Ah[cur], Al[cur], same ? Ah[cur] : Bh_[cur], same ? Al[cur] : Bl_[cur], wr, wc, lane, acc);
        if (it + 1 < nt) {
            int nx = cur ^ 1;
            commit_pl(fa, Ah[nx], Al[nx], t);
            if (!same) commit_pl(fb, Bh_[nx], Bl_[nx], t);
            __syncthreads();
        }
    }
    #pragma unroll
    for (int fr = 0; fr < 2; ++fr)
        #pragma unroll
        for (int fc = 0; fc < 2; ++fc) {
            int row = wr * 32 + fr * 16 + ((lane >> 4) << 2);
            int col = wc * 32 + fc * 16 + (lane & 15);
            #pragma unroll
            for (int r = 0; r < 4; ++r)
                C[(size_t)(row + r) * 64 + col] = acc[fr][fc][r];
        }
}

__global__ __launch_bounds__(256) void gcombine(const float* __restrict__ Gp,
                                                const u16* Uh, const u16* Ul, const u16* Vh, const u16* Vl,
                                                float* Sd, float* Nt64, float* Nt128, float* Nt256, float* Nt512) {
    int tt = blockIdx.x;
    GJob g = gdecode(tt, Uh, Ul, Vh, Vl, Sd, Nt64, Nt128, Nt256, Nt512);
    const float* base = Gp + (size_t)tt * 8 * 4096;
    for (int i = threadIdx.x; i < 4096; i += 256) {
        float s = 0.0f;
        #pragma unroll
        for (int ks = 0; ks < 8; ++ks) s += base[(size_t)ks * 4096 + i];
        g.out[(size_t)(i >> 6) * g.ldO + (i & 63)] = s;
    }
}

// ---------------- diag 64-block inverse ----------------
__global__ __launch_bounds__(64) void diag_inv64(const float* __restrict__ Sd,
                                                 float* __restrict__ Ttu, float* __restrict__ Ttv) {
    int j = blockIdx.x;
    int y = blockIdx.y;
    const float* S = Sd + (size_t)y * 4096;
    float* T; int ldT, off;
    if (y < 16) { T = Ttu; ldT = CI; off = 64 * y; }
    else        { T = Ttv; ldT = CO; off = 64 * (y - 16); }
    float* Trow = T + (size_t)(off + j) * ldT + off;
    int l = threadIdx.x;
    float x = (l == j) ? 2.0f : 0.0f;
    float a = 0.0f;
    int jpad = (j + 7) & ~7;
    float q0=0,q1=0,q2=0,q3=0,q4=0,q5=0,q6=0,q7=0;
#define LR(Q, R) { int _r = (R); if (_r >= 1 && _r <= j) Q = S[(size_t)_r * 64 + l]; }
    LR(q0, jpad - 0) LR(q1, jpad - 1) LR(q2, jpad - 2) LR(q3, jpad - 3)
    LR(q4, jpad - 4) LR(q5, jpad - 5) LR(q6, jpad - 6) LR(q7, jpad - 7)
#define ST(Q) { \
    float yk = __shfl(x, k); \
    a = fmaf(Q, yk, a); \
    if (k <= j && l == k - 1) x = -2.0f * a; \
    int pr = k - 8; \
    if (pr >= 1) Q = S[(size_t)pr * 64 + l]; \
    --k; }
    int k = jpad;
    int ng = jpad >> 3;
    for (int g = 0; g < ng; ++g) {
        ST(q0) ST(q1) ST(q2) ST(q3) ST(q4) ST(q5) ST(q6) ST(q7)
    }
#undef ST
#undef LR
    Trow[l] = x;
}

// ---------------- merge level s=64: fused (tmp = Nt@Tt0 ; Ot = -Tt1@tmp) ----------------
__global__ __launch_bounds__(256) void merge64_fused(const float* __restrict__ Nt64,
                                                     float* __restrict__ Ttu, float* __restrict__ Ttv) {
    int p = blockIdx.x;
    bool isU = p < 8;
    float* Tt = isU ? Ttu : Ttv;
    int ldT = isU ? CI : CO;
    int pp = isU ? p : p - 8;
    int c0 = 128 * pp, r1 = c0 + 64;
    __shared__ float A[64][65], B[64][65], Tm[64][65];
    int t = threadIdx.x;
    int r = t >> 2, c = (t & 3) * 16;
    #pragma unroll
    for (int j = 0; j < 16; ++j) A[r][c + j] = Nt64[(size_t)p * 4096 + (size_t)r * 64 + c + j];
    #pragma unroll
    for (int j = 0; j < 16; ++j) B[r][c + j] = Tt[(size_t)(c0 + r) * ldT + c0 + c + j];
    __syncthreads();
    float acc[16];
    #pragma unroll
    for (int j = 0; j < 16; ++j) acc[j] = 0.0f;
    for (int k = 0; k < 64; ++k) {
        float av = A[r][k];
        #pragma unroll
        for (int j = 0; j < 16; ++j) acc[j] = fmaf(av, B[k][c + j], acc[j]);
    }
    __syncthreads();
    #pragma unroll
    for (int j = 0; j < 16; ++j) Tm[r][c + j] = acc[j];
    #pragma unroll
    for (int j = 0; j < 16; ++j) A[r][c + j] = Tt[(size_t)(r1 + r) * ldT + r1 + c + j];
    __syncthreads();
    #pragma unroll
    for (int j = 0; j < 16; ++j) acc[j] = 0.0f;
    for (int k = 0; k < 64; ++k) {
        float av = A[r][k];
        #pragma unroll
        for (int j = 0; j < 16; ++j) acc[j] = fmaf(av, Tm[k][c + j], acc[j]);
    }
    #pragma unroll
    for (int j = 0; j < 16; ++j)
        Tt[(size_t)(r1 + r) * ldT + c0 + c + j] = -acc[j];
}

// ---------------- fp32 split-K merge GEMMs ----------------
__device__ __forceinline__ void fgemm_sk_body(const float* __restrict__ A, int lda,
                                              const float* __restrict__ B, int ldb,
                                              float* __restrict__ P, int kb, int klen) {
    int m0 = blockIdx.y * 64, n0 = blockIdx.x * 64;
    __shared__ float As[16][64];
    __shared__ float Bs[16][64];
    int tid = threadIdx.x;
    int tm = (tid >> 4) * 8, tn = (tid & 15) * 4;
    int ar = tid >> 2, ac = (tid & 3) * 4;
    int bk = tid >> 4, bn = (tid & 15) * 4;
    float acc[8][4] = {};
    for (int k0 = kb; k0 < kb + klen; k0 += 16) {
        #pragma unroll
        for (int p = 0; p < 2; ++p) {
            int r = ar + p * 32;
            fx4 av = *(const fx4*)(A + (size_t)(m0 + r) * lda + k0 + ac);
            As[ac + 0][r] = av[0]; As[ac + 1][r] = av[1]; As[ac + 2][r] = av[2]; As[ac + 3][r] = av[3];
        }
        #pragma unroll
        for (int p = 0; p < 2; ++p) {
            int kk = bk + p * 8;
            *(fx4*)&Bs[kk][bn] = *(const fx4*)(B + (size_t)(k0 + kk) * ldb + n0 + bn);
        }
        __syncthreads();
        #pragma unroll
        for (int k = 0; k < 16; ++k) {
            fx4 alo = *(const fx4*)&As[k][tm];
            fx4 ahi = *(const fx4*)&As[k][tm + 4];
            fx4 bv  = *(const fx4*)&Bs[k][tn];
            float aa[8] = {alo[0], alo[1], alo[2], alo[3], ahi[0], ahi[1], ahi[2], ahi[3]};
            float bb[4] = {bv[0], bv[1], bv[2], bv[3]};
            #pragma unroll
            for (int i = 0; i < 8; ++i)
                #pragma unroll
                for (int jj = 0; jj < 4; ++jj) acc[i][jj] = fmaf(aa[i], bb[jj], acc[i][jj]);
        }
        __syncthreads();
    }
    #pragma unroll
    for (int i = 0; i < 8; ++i) {
        fx4 v = { acc[i][0], acc[i][1], acc[i][2], acc[i][3] };
        *(fx4*)(P + (size_t)(tm + i) * 64 + tn) = v;
    }
}

__global__ __launch_bounds__(128) void merge_a_sk(const float* __restrict__ NtL, int s, int KS,
                                                  const float* __restrict__ Ttu, const float* __restrict__ Ttv,
                                                  int npu, float* __restrict__ Mp) {
    int z = blockIdx.z;
    int pair = z / KS, ks = z % KS;
    const float* Tt; int ldT, p;
    if (pair < npu) { Tt = Ttu; ldT = CI; p = pair; } else { Tt = Ttv; ldT = CO; p = pair - npu; }
    int c0 = 2 * s * p;
    int gx = s >> 6;
    int tile = (pair * gx + blockIdx.y) * gx + blockIdx.x;
    int klen = s / KS;
    fgemm_sk_body(NtL + (size_t)pair * s * s, s, Tt + (size_t)c0 * ldT + c0, ldT,
                  Mp + ((size_t)tile * KS + ks) * 4096, ks * klen, klen);
}

__global__ __launch_bounds__(128) void merge_b_sk(const float* __restrict__ tmp, int s, int KS,
                                                  const float* __restrict__ Ttu, const float* __restrict__ Ttv,
                                                  int npu, float* __restrict__ Mp) {
    int z = blockIdx.z;
    int pair = z / KS, ks = z % KS;
    const float* Tt; int ldT, p;
    if (pair < npu) { Tt = Ttu; ldT = CI; p = pair; } else { Tt = Ttv; ldT = CO; p = pair - npu; }
    int c0 = 2 * s * p, r1 = c0 + s;
    int gx = s >> 6;
    int tile = (pair * gx + blockIdx.y) * gx + blockIdx.x;
    int klen = s / KS;
    fgemm_sk_body(Tt + (size_t)r1 * ldT + r1, ldT, tmp + (size_t)pair * s * s, s,
                  Mp + ((size_t)tile * KS + ks) * 4096, ks * klen, klen);
}

__global__ __launch_bounds__(256) void macomb(const float* __restrict__ Mp, int KS, int s,
                                              float* __restrict__ tmp) {
    int tile = blockIdx.x;
    int gx = s >> 6, per = gx * gx;
    int pair = tile / per, rem = tile % per, by = rem / gx, bx = rem % gx;
    float* dst = tmp + (size_t)pair * s * s + (size_t)(by * 64) * s + bx * 64;
    const float* base = Mp + (size_t)tile * KS * 4096;
    for (int i = threadIdx.x; i < 4096; i += 256) {
        float v = 0.0f;
        for (int k = 0; k < KS; ++k) v += base[(size_t)k * 4096 + i];
        dst[(size_t)(i >> 6) * s + (i & 63)] = v;
    }
}

__global__ __launch_bounds__(256) void mbcomb(const float* __restrict__ Mp, int KS, int s, int npu,
                                              float* __restrict__ Ttu, float* __restrict__ Ttv) {
    int tile = blockIdx.x;
    int gx = s >> 6, per = gx * gx;
    int pair = tile / per, rem = tile % per, by = rem / gx, bx = rem % gx;
    float* Tt; int ldT, p;
    if (pair < npu) { Tt = Ttu; ldT = CI; p = pair; } else { Tt = Ttv; ldT = CO; p = pair - npu; }
    int c0 = 2 * s * p, r1 = c0 + s;
    float* dst = Tt + (size_t)(r1 + by * 64) * ldT + c0 + bx * 64;
    const float* base = Mp + (size_t)tile * KS * 4096;
    for (int i = threadIdx.x; i < 4096; i += 256) {
        float v = 0.0f;
        for (int k = 0; k < KS; ++k) v += base[(size_t)k * 4096 + i];
        dst[(size_t)(i >> 6) * ldT + (i & 63)] = -v;
    }
}

// ---------------- split-K chain GEMMs, double-buffered ----------------
__global__ __launch_bounds__(256) void gemm_pp_sk(const u16* __restrict__ Ah_, const u16* __restrict__ Al_, int ldA,
                                                  const u16* __restrict__ Bh0, const u16* __restrict__ Bl0, int ldB,
                                                  float* __restrict__ Pp, int kchunk) {
    int N = gridDim.x * 64;
    size_t MN = (size_t)gridDim.x * gridDim.y * 4096;
    float* C = Pp + (size_t)blockIdx.z * MN;
    int kb = blockIdx.z * kchunk;
    __shared__ u16 Ah[2][64][LP], Al[2][64][LP], Bh_[2][64][LP], Bl_[2][64][LP];
    int t = threadIdx.x, lane = t & 63, w = t >> 6, wr = w >> 1, wc = w & 1;
    int m0 = blockIdx.y * 64, n0 = blockIdx.x * 64;
    fx4 acc[2][2] = {};
    PF fa = fetch_pl(Ah_, Al_, ldA, m0, kb, t);
    PF fb = fetch_pl(Bh0, Bl0, ldB, n0, kb, t);
    commit_pl(fa, Ah[0], Al[0], t);
    commit_pl(fb, Bh_[0], Bl_[0], t);
    __syncthreads();
    int nt = kchunk >> 5;
    for (int it = 0; it < nt; ++it) {
        int cur = it & 1;
        if (it + 1 < nt) {
            int k0 = kb + (it + 1) * 32;
            fa = fetch_pl(Ah_, Al_, ldA, m0, k0, t);
            fb = fetch_pl(Bh0, Bl0, ldB, n0, k0, t);
        }
        mma_step(Ah[cur], Al[cur], Bh_[cur], Bl_[cur], wr, wc, lane, acc);
        if (it + 1 < nt) {
            int nx = cur ^ 1;
            commit_pl(fa, Ah[nx], Al[nx], t);
            commit_pl(fb, Bh_[nx], Bl_[nx], t);
            __syncthreads();
        }
    }
    #pragma unroll
    for (int fr = 0; fr < 2; ++fr)
        #pragma unroll
        for (int fc = 0; fc < 2; ++fc) {
            int row = m0 + wr * 32 + fr * 16 + ((lane >> 4) << 2);
            int col = n0 + wc * 32 + fc * 16 + (lane & 15);
            #pragma unroll
            for (int r = 0; r < 4; ++r)
                C[(size_t)(row + r) * N + col] = acc[fr][fc][r];
        }
}

__global__ __launch_bounds__(256) void gemm_fp_sk(const float* __restrict__ A, int ldA,
                                                  const u16* __restrict__ Bh0, const u16* __restrict__ Bl0, int ldB,
                                                  float* __restrict__ Pp, int kchunk) {
    int N = gridDim.x * 64;
    size_t MN = (size_t)gridDim.x * gridDim.y * 4096;
    float* C = Pp + (size_t)blockIdx.z * MN;
    int kb = blockIdx.z * kchunk;
    __shared__ u16 Ah[2][64][LP], Al[2][64][LP], Bh_[2][64][LP], Bl_[2][64][LP];
    int t = threadIdx.x, lane = t & 63, w = t >> 6, wr = w >> 1, wc = w & 1;
    int m0 = blockIdx.y * 64, n0 = blockIdx.x * 64;
    fx4 acc[2][2] = {};
    FF fa = fetch_f32(A, ldA, m0, kb, t);
    PF fb = fetch_pl(Bh0, Bl0, ldB, n0, kb, t);
    commit_f32(fa, Ah[0], Al[0], t);
    commit_pl(fb, Bh_[0], Bl_[0], t);
    __syncthreads();
    int nt = kchunk >> 5;
    for (int it = 0; it < nt; ++it) {
        int cur = it & 1;
        if (it + 1 < nt) {
            int k0 = kb + (it + 1) * 32;
            fa = fetch_f32(A, ldA, m0, k0, t);
            fb = fetch_pl(Bh0, Bl0, ldB, n0, k0, t);
        }
        mma_step(Ah[cur], Al[cur], Bh_[cur], Bl_[cur], wr, wc, lane, acc);
        if (it + 1 < nt) {
            int nx = cur ^ 1;
            commit_f32(fa, Ah[nx], Al[nx], t);
            commit_pl(fb, Bh_[nx], Bl_[nx], t);
            __syncthreads();
        }
    }
    #pragma unroll
    for (int fr = 0; fr < 2; ++fr)
        #pragma unroll
        for (int fc = 0; fc < 2; ++fc) {
            int row = m0 + wr * 32 + fr * 16 + ((lane >> 4) << 2);
            int col = n0 + wc * 32 + fc * 16 + (lane & 15);
            #pragma unroll
            for (int r = 0; r < 4; ++r)
                C[(size_t)(row + r) * N + col] = acc[fr][fc][r];
        }
}

// MODE: 0 C=sum ; 1 C=I-sum ; 2 C=aux-sum ; 3 C-=sum ; 4 C=(col<CI?aux:0)-sum
template<int MODE>
__global__ __launch_bounds__(256) void combine(const float* __restrict__ Pp, int S,
                                               const float* __restrict__ aux, int ldaux,
                                               float* __restrict__ C, int N) {
    size_t MN = (size_t)gridDim.x * 2048;
    int gid = blockIdx.x * 256 + threadIdx.x;
    size_t idx = (size_t)gid * 8;
    int nv = N >> 3;
    int row = gid / nv, col = (gid % nv) * 8;
    fx4 s0 = *(const fx4*)(Pp + idx);
    fx4 s1 = *(const fx4*)(Pp + idx + 4);
    for (int s = 1; s < S; ++s) {
        const float* p = Pp + (size_t)s * MN + idx;
        s0 += *(const fx4*)p;
        s1 += *(const fx4*)(p + 4);
    }
    float out[8];
    #pragma unroll
    for (int j = 0; j < 8; ++j) {
        float a = (j < 4) ? s0[j] : s1[j - 4];
        if (MODE == 0)      out[j] = a;
        else if (MODE == 1) out[j] = ((col + j) == row ? 1.0f : 0.0f) - a;
        else if (MODE == 2) out[j] = aux[(size_t)row * ldaux + col + j] - a;
        else if (MODE == 3) out[j] = C[(size_t)row * N + col + j] - a;
        else                out[j] = ((col + j) < CI ? aux[(size_t)row * ldaux + col + j] : 0.0f) - a;
    }
    *(fx4*)(C + (size_t)row * N + col)     = *(fx4*)&out[0];
    *(fx4*)(C + (size_t)row * N + col + 4) = *(fx4*)&out[4];
}

extern "C" void kernel_launch(void* const* d_in, const int* in_sizes, int n_in,
                              void* d_out, int out_size, void* d_ws, size_t ws_size,
                              hipStream_t stream) {
    const float* U = (const float*)d_in[0];   // 1024x1024
    const float* V = (const float*)d_in[1];   // 2048x2048
    float* W = (float*)d_out;                 // 1024x2048

    char* ws = (char*)d_ws;
    u16*   Unth = (u16*)  (ws + ((size_t)0   << 20));  // 2 MB
    u16*   Untl = (u16*)  (ws + ((size_t)2   << 20));
    u16*   Unh  = (u16*)  (ws + ((size_t)4   << 20));
    u16*   Unl  = (u16*)  (ws + ((size_t)6   << 20));
    u16*   Vnth = (u16*)  (ws + ((size_t)8   << 20));  // 8 MB
    u16*   Vntl = (u16*)  (ws + ((size_t)16  << 20));
    u16*   Vnh  = (u16*)  (ws + ((size_t)24  << 20));
    u16*   Vnl  = (u16*)  (ws + ((size_t)32  << 20));
    float* Ttu  = (float*)(ws + ((size_t)40  << 20));  // 4 MB
    float* Ttv  = (float*)(ws + ((size_t)44  << 20));  // 16 MB
    u16*   Mtuh = (u16*)  (ws + ((size_t)60  << 20));  // 2 MB
    u16*   Mtul = (u16*)  (ws + ((size_t)62  << 20));
    u16*   Mtvh = (u16*)  (ws + ((size_t)64  << 20));  // 8 MB
    u16*   Mtvl = (u16*)  (ws + ((size_t)72  << 20));
    float* Sd   = (float*)(ws + ((size_t)80  << 20));  // 0.75 MB
    float* NtA  = (float*)(ws + ((size_t)81  << 20));  // 4.85 MB
    float* tmp  = (float*)(ws + ((size_t)86  << 20));  // 2 MB
    float* X1   = (float*)(ws + ((size_t)88  << 20));  // 2 MB
    float* Qp   = (float*)(ws + ((size_t)90  << 20));  // 4 MB
    float* H1u  = (float*)(ws + ((size_t)94  << 20));  // 2 MB
    float* H2u  = (float*)(ws + ((size_t)96  << 20));  // 2 MB
    float* Qu   = (float*)(ws + ((size_t)98  << 20));  // 4 MB
    float* H1   = (float*)(ws + ((size_t)102 << 20));  // 4 MB
    float* H2   = (float*)(ws + ((size_t)106 << 20));  // 4 MB
    float* H3   = (float*)(ws + ((size_t)110 << 20));  // 4 MB
    float* H4   = (float*)(ws + ((size_t)114 << 20));  // 4 MB
    float* n2u  = (float*)(ws + ((size_t)118 << 20));  // 12 KB
    float* n2v  = n2u + CI;
    float* Pp   = (float*)(ws + ((size_t)120 << 20));  // 16 MB chain split-K partials
    float* Gp   = (float*)(ws + ((size_t)120 << 20));  // 45 MB gram/nt partials (consumed pre-chain)
    float* Mp   = Gp;

    float* Nt64  = NtA;
    float* Nt128 = NtA + 98304;
    float* Nt256 = NtA + 294912;
    float* Nt512 = NtA + 688128;

    // 1) column norms
    hipMemsetAsync(n2u, 0, (CI + CO) * sizeof(float), stream);
    colnorm2<<<dim3(CI / 256, CI / 64), dim3(256), 0, stream>>>(U, n2u, CI);
    colnorm2<<<dim3(CO / 256, CO / 64), dim3(256), 0, stream>>>(V, n2v, CO);

    // 2) normalized planes
    trans_planes_n<<<dim3(CI / 32, CI / 32), dim3(256), 0, stream>>>(U, CI, n2u, Unth, Untl);
    trans_planes_n<<<dim3(CO / 32, CO / 32), dim3(256), 0, stream>>>(V, CO, n2v, Vnth, Vntl);
    planes_n<<<dim3(CI * CI / 2048), dim3(256), 0, stream>>>(U, CI, n2u, Unh, Unl);
    planes_n<<<dim3(CO * CO / 2048), dim3(256), 0, stream>>>(V, CO, n2v, Vnh, Vnl);

    // 3) ALL gram + Nt tiles in one split-K dispatch + one combine
    gram_nt_sk<<<dim3(344, 8), dim3(256), 0, stream>>>(Unth, Untl, Vnth, Vntl,
                                                       Sd, Nt64, Nt128, Nt256, Nt512, Gp);
    gcombine<<<dim3(344), dim3(256), 0, stream>>>(Gp, Unth, Untl, Vnth, Vntl,
                                                  Sd, Nt64, Nt128, Nt256, Nt512);

    // 4) blocked triangular inverse
    hipMemsetAsync(Ttu, 0, (size_t)20 << 20, stream);
    diag_inv64<<<dim3(64, 48), dim3(64), 0, stream>>>(Sd, Ttu, Ttv);
    merge64_fused<<<dim3(24), dim3(256), 0, stream>>>(Nt64, Ttu, Ttv);
    merge_a_sk<<<dim3(2, 2, 48), dim3(128), 0, stream>>>(Nt128, 128, 4, Ttu, Ttv, 4, Mp);
    macomb<<<dim3(48), dim3(256), 0, stream>>>(Mp, 4, 128, tmp);
    merge_b_sk<<<dim3(2, 2, 48), dim3(128), 0, stream>>>(tmp, 128, 4, Ttu, Ttv, 4, Mp);
    mbcomb<<<dim3(48), dim3(256), 0, stream>>>(Mp, 4, 128, 4, Ttu, Ttv);
    merge_a_sk<<<dim3(4, 4, 24), dim3(128), 0, stream>>>(Nt256, 256, 4, Ttu, Ttv, 2, Mp);
    macomb<<<dim3(96), dim3(256), 0, stream>>>(Mp, 4, 256, tmp);
    merge_b_sk<<<dim3(4, 4, 24), dim3(128), 0, stream>>>(tmp, 256, 4, Ttu, Ttv, 2, Mp);
    mbcomb<<<dim3(96), dim3(256), 0, stream>>>(Mp, 4, 256, 2, Ttu, Ttv);
    merge_a_sk<<<dim3(8, 8, 16), dim3(128), 0, stream>>>(Nt512, 512, 8, Ttu, Ttv, 0, Mp);
    macomb<<<dim3(128), dim3(256), 0, stream>>>(Mp, 8, 512, tmp);
    merge_b_sk<<<dim3(8, 8, 16), dim3(128), 0, stream>>>(tmp, 512, 8, Ttu, Ttv, 0, Mp);
    mbcomb<<<dim3(128), dim3(256), 0, stream>>>(Mp, 8, 512, 0, Ttu, Ttv);

    // 5) T planes
    planes_conv<<<dim3(CI * CI / 2048), dim3(256), 0, stream>>>(Ttu, Mtuh, Mtul);
    planes_conv<<<dim3(CO * CO / 2048), dim3(256), 0, stream>>>(Ttv, Mtvh, Mtvl);

    // 6) U series (verified round 10/12)
    gemm_pp_sk<<<dim3(8, 16, 4), dim3(256), 0, stream>>>(Unh, Unl, CI, Mtuh, Mtul, CI, Pp, 128);
    combine<0><<<dim3(CI * 512 / 2048), dim3(256), 0, stream>>>(Pp, 4, nullptr, 0, X1, 512);
    gemm_fp_sk<<<dim3(16, 16, 4), dim3(256), 0, stream>>>(X1, 512, Unh, Unl, CI, Pp, 128);
    combine<1><<<dim3(CI * CI / 2048), dim3(256), 0, stream>>>(Pp, 4, nullptr, 0, Qp, CI);
    gemm_fp_sk<<<dim3(8, 16, 4), dim3(256), 0, stream>>>(Qp, CI, Unth + (size_t)512 * CI, Untl + (size_t)512 * CI, CI, Pp, 256);
    combine<0><<<dim3(CI * 512 / 2048), dim3(256), 0, stream>>>(Pp, 4, nullptr, 0, H1u, 512);
    gemm_fp_sk<<<dim3(8, 16, 4), dim3(256), 0, stream>>>(H1u, 512, Mtuh + (size_t)512 * CI + 512,
                                                         Mtul + (size_t)512 * CI + 512, CI, Pp, 128);
    combine<0><<<dim3(CI * 512 / 2048), dim3(256), 0, stream>>>(Pp, 4, nullptr, 0, H2u, 512);
    gemm_fp_sk<<<dim3(16, 16, 4), dim3(256), 0, stream>>>(H2u, 512, Unh + 512, Unl + 512, CI, Pp, 128);
    combine<2><<<dim3(CI * CI / 2048), dim3(256), 0, stream>>>(Pp, 4, Qp, CI, Qu, CI);

    // 7) V series (verified round 10/12)
    gemm_fp_sk<<<dim3(16, 16, 4), dim3(256), 0, stream>>>(Qu, CI, Vnth, Vntl, CO, Pp, 256);
    combine<0><<<dim3(CI * CI / 2048), dim3(256), 0, stream>>>(Pp, 4, nullptr, 0, H1, CI);
    gemm_fp_sk<<<dim3(16, 16, 4), dim3(256), 0, stream>>>(H1, CI, Mtvh, Mtvl, CO, Pp, 256);
    combine<0><<<dim3(CI * CI / 2048), dim3(256), 0, stream>>>(Pp, 4, nullptr, 0, H2, CI);
    gemm_fp_sk<<<dim3(32, 16, 2), dim3(256), 0, stream>>>(H2, CI, Vnh, Vnl, CO, Pp, 512);
    combine<4><<<dim3(CI * CO / 2048), dim3(256), 0, stream>>>(Pp, 2, Qu, CI, W, CO);
    gemm_fp_sk<<<dim3(16, 16, 4), dim3(256), 0, stream>>>(W, CO, Vnth + (size_t)1024 * CO, Vntl + (size_t)1024 * CO, CO, Pp, 512);
    combine<0><<<dim3(CI * CI / 2048), dim3(256), 0, stream>>>(Pp, 4, nullptr, 0, H3, CI);
    gemm_fp_sk<<<dim3(16, 16, 4), dim3(256), 0, stream>>>(H3, CI, Mtvh + (size_t)1024 * CO + 1024,
                                                          Mtvl + (size_t)1024 * CO + 1024, CO, Pp, 256);
    combine<0><<<dim3(CI * CI / 2048), dim3(256), 0, stream>>>(Pp, 4, nullptr, 0, H4, CI);
    gemm_fp_sk<<<dim3(32, 16, 2), dim3(256), 0, stream>>>(H4, CI, Vnh + 1024, Vnl + 1024, CO, Pp, 512);
    combine<3><<<dim3(CI * CO / 2048), dim3(256), 0, stream>>>(Pp, 2, nullptr, 0, W, CO);
}